// Round 4
// baseline (321.937 us; speedup 1.0000x reference)
//
#include <hip/hip_runtime.h>
#include <hip/hip_bf16.h>

// Problem dims
#define NT 8192      // N*H*W tokens
#define DM 256
#define SS 16
#define HH 64
#define WW 64

typedef unsigned short u16;
typedef __attribute__((ext_vector_type(8))) short short8;  // 8 x bf16 mfma frag
typedef __attribute__((ext_vector_type(4))) float f4;

__device__ __forceinline__ float bf2f(u16 u){
  union { unsigned int i; float f; } v; v.i = ((unsigned int)u) << 16; return v.f;
}
__device__ __forceinline__ u16 f2bf(float f){
  union { float f; unsigned int i; } v; v.f = f;
  unsigned int r = (v.i + 0x7fffu + ((v.i >> 16) & 1u)) >> 16;
  return (u16)r;
}

// ---------------------------------------------------------------------------
// Transpose fp32 [R,C] -> bf16 hi/lo planes [C,R]  (x = hi + lo, |err|<=2^-17)
// ---------------------------------------------------------------------------
__global__ __launch_bounds__(256) void transpose3_k(const float* __restrict__ src,
                                                    u16* __restrict__ dh,
                                                    u16* __restrict__ dl,
                                                    int R, int C){
  __shared__ float t[32][33];
  int tx = threadIdx.x & 31, ty = threadIdx.x >> 5;
  int c0 = blockIdx.x * 32, r0 = blockIdx.y * 32;
  for (int i = ty; i < 32; i += 8) t[i][tx] = src[(size_t)(r0 + i) * C + c0 + tx];
  __syncthreads();
  for (int i = ty; i < 32; i += 8){
    float x = t[tx][i];
    u16 h = f2bf(x);
    size_t idx = (size_t)(c0 + i) * R + r0 + tx;
    dh[idx] = h;
    dl[idx] = f2bf(x - bf2f(h));
  }
}

// ---------------------------------------------------------------------------
// Fold W_kvp/b_kvp through Wk (or Wv): out = [Wkk0(256), Wkk1(256), bias2(256)]
// ---------------------------------------------------------------------------
__global__ __launch_bounds__(256) void prepkv_k(const float* __restrict__ Wkvp,
                                                const float* __restrict__ bkvp,
                                                const float* __restrict__ Wx,
                                                const float* __restrict__ bx,
                                                float* __restrict__ outc){
  int e = threadIdx.x;
  float a0 = 0.f, a1 = 0.f, ab = 0.f;
  for (int d = 0; d < 256; d++){
    float w = Wx[d * 256 + e];
    a0 += Wkvp[d] * w;        // W_kvp[0][d]
    a1 += Wkvp[256 + d] * w;  // W_kvp[1][d]
    ab += bkvp[d] * w;
  }
  outc[e] = a0; outc[256 + e] = a1; outc[512 + e] = ab + bx[e];
}

// ---------------------------------------------------------------------------
// Offsets: off = 60*sigmoid(hs @ W_off + b_off) - 30 ; loc = clip(ref+off,0,63)
// ---------------------------------------------------------------------------
__global__ __launch_bounds__(256) void offsets_k(const float* __restrict__ hs,
                                                 const float* __restrict__ Woff,
                                                 const float* __restrict__ boff,
                                                 float* __restrict__ off,
                                                 float* __restrict__ loc){
  __shared__ float hsl[8][256];
  __shared__ float wl[256 * 32];
  const int tid = threadIdx.x;
  const int t0 = blockIdx.x * 8;
  for (int i = tid; i < 8192; i += 256) wl[i] = Woff[i];
  for (int i = tid; i < 2048; i += 256) hsl[i >> 8][i & 255] = hs[(size_t)t0 * 256 + i];
  __syncthreads();
  const int g = tid >> 5, o = tid & 31;
  float acc = 0.f;
  #pragma unroll 8
  for (int d = 0; d < 256; d++) acc += hsl[g][d] * wl[d * 32 + o];
  acc += boff[o];
  float sg = 1.f / (1.f + expf(-acc));
  float of = 60.f * sg - 30.f;
  int tok = t0 + g;
  int hh = (tok >> 6) & 63, ww = tok & 63;
  float base = (o & 1) ? (float)ww : (float)hh;
  float l = fminf(fmaxf(base + of, 0.f), 63.f);
  off[tok * 32 + o] = of;
  loc[tok * 32 + o] = l;
}

// ---------------------------------------------------------------------------
// Split-precision MFMA GEMM: C[M,N] = A[M,K](fp32) * Bt[N,K](bf16 hi/lo)^T
//   A split hi/lo at LDS staging; product = Ah*Bh + Ah*Bl + Al*Bh  (~2^-17)
// 64x64 tile, 4 waves, each a 32x32 subtile of 2x2 16x16x32 mfmas x3.
// EPI 0: fp32 out + bias.  EPI 2: gelu(tanh) -> fp32 out.
// ---------------------------------------------------------------------------
template<int EPI>
__global__ __launch_bounds__(256) void gemm3_k(const float* __restrict__ A,
                                               const u16* __restrict__ Bth,
                                               const u16* __restrict__ Btl,
                                               const float* __restrict__ bias,
                                               float* __restrict__ C,
                                               int M, int N, int K){
  __shared__ __align__(16) u16 Ah[4][64][8];
  __shared__ __align__(16) u16 Alo[4][64][8];
  __shared__ __align__(16) u16 Bh[4][64][8];
  __shared__ __align__(16) u16 Blo[4][64][8];
  const int m0 = blockIdx.x << 6, n0 = blockIdx.y << 6;
  const int tid = threadIdx.x;
  const int lane = tid & 63, wave = tid >> 6;
  const int quad = lane >> 4, l15 = lane & 15;
  const int wm = (wave >> 1) << 5, wn = (wave & 1) << 5;
  const int r = tid >> 2, qd = tid & 3;
  const float* Ap = A + (size_t)(m0 + r) * K + qd * 8;
  const u16* Bhp = Bth + (size_t)(n0 + r) * K + qd * 8;
  const u16* Blp = Btl + (size_t)(n0 + r) * K + qd * 8;
  f4 acc[2][2] = {};
  for (int k0 = 0; k0 < K; k0 += 32){
    float af[8];
    *(f4*)(af)     = *(const f4*)(Ap + k0);
    *(f4*)(af + 4) = *(const f4*)(Ap + k0 + 4);
    int4 bh = *(const int4*)(Bhp + k0);
    int4 bl = *(const int4*)(Blp + k0);
    short8 hi8, lo8;
    #pragma unroll
    for (int j = 0; j < 8; j++){
      u16 h = f2bf(af[j]);
      hi8[j] = (short)h;
      lo8[j] = (short)f2bf(af[j] - bf2f(h));
    }
    __syncthreads();
    *(short8*)(&Ah[qd][r][0])  = hi8;
    *(short8*)(&Alo[qd][r][0]) = lo8;
    *(int4*)(&Bh[qd][r][0])    = bh;
    *(int4*)(&Blo[qd][r][0])   = bl;
    __syncthreads();
    short8 ah0 = *(const short8*)(&Ah[quad][wm + l15][0]);
    short8 ah1 = *(const short8*)(&Ah[quad][wm + 16 + l15][0]);
    short8 al0 = *(const short8*)(&Alo[quad][wm + l15][0]);
    short8 al1 = *(const short8*)(&Alo[quad][wm + 16 + l15][0]);
    short8 bh0 = *(const short8*)(&Bh[quad][wn + l15][0]);
    short8 bh1 = *(const short8*)(&Bh[quad][wn + 16 + l15][0]);
    short8 bl0 = *(const short8*)(&Blo[quad][wn + l15][0]);
    short8 bl1 = *(const short8*)(&Blo[quad][wn + 16 + l15][0]);
    acc[0][0] = __builtin_amdgcn_mfma_f32_16x16x32_bf16(al0, bh0, acc[0][0], 0, 0, 0);
    acc[0][0] = __builtin_amdgcn_mfma_f32_16x16x32_bf16(ah0, bl0, acc[0][0], 0, 0, 0);
    acc[0][0] = __builtin_amdgcn_mfma_f32_16x16x32_bf16(ah0, bh0, acc[0][0], 0, 0, 0);
    acc[0][1] = __builtin_amdgcn_mfma_f32_16x16x32_bf16(al0, bh1, acc[0][1], 0, 0, 0);
    acc[0][1] = __builtin_amdgcn_mfma_f32_16x16x32_bf16(ah0, bl1, acc[0][1], 0, 0, 0);
    acc[0][1] = __builtin_amdgcn_mfma_f32_16x16x32_bf16(ah0, bh1, acc[0][1], 0, 0, 0);
    acc[1][0] = __builtin_amdgcn_mfma_f32_16x16x32_bf16(al1, bh0, acc[1][0], 0, 0, 0);
    acc[1][0] = __builtin_amdgcn_mfma_f32_16x16x32_bf16(ah1, bl0, acc[1][0], 0, 0, 0);
    acc[1][0] = __builtin_amdgcn_mfma_f32_16x16x32_bf16(ah1, bh0, acc[1][0], 0, 0, 0);
    acc[1][1] = __builtin_amdgcn_mfma_f32_16x16x32_bf16(al1, bh1, acc[1][1], 0, 0, 0);
    acc[1][1] = __builtin_amdgcn_mfma_f32_16x16x32_bf16(ah1, bl1, acc[1][1], 0, 0, 0);
    acc[1][1] = __builtin_amdgcn_mfma_f32_16x16x32_bf16(ah1, bh1, acc[1][1], 0, 0, 0);
  }
  #pragma unroll
  for (int ms = 0; ms < 2; ms++)
  #pragma unroll
  for (int ns = 0; ns < 2; ns++){
    int col = n0 + wn + ns * 16 + l15;
    float bval = bias ? bias[col] : 0.f;
    int rowb = m0 + wm + ms * 16 + quad * 4;
    #pragma unroll
    for (int rg = 0; rg < 4; rg++){
      float v = acc[ms][ns][rg] + bval;
      size_t idx = (size_t)(rowb + rg) * N + col;
      if (EPI == 0){
        C[idx] = v;
      } else {
        float t = v + 0.044715f * v * v * v;
        float g = 0.5f * v * (1.f + tanhf(0.7978845608f * t));
        C[idx] = g;
      }
    }
  }
}

// ---------------------------------------------------------------------------
// Attention: one wave per token. lane holds dims [4*lane, 4*lane+4) -> head
// group = 16 lanes. Bilinear gather of projected EK/EV rows (coalesced).
// All fp32; output fp32.
// ---------------------------------------------------------------------------
__global__ __launch_bounds__(256) void attn_k(const float* __restrict__ q,
                                              const float* __restrict__ EK,
                                              const float* __restrict__ EV,
                                              const float* __restrict__ offb,
                                              const float* __restrict__ locb,
                                              const float* __restrict__ kvc,
                                              float* __restrict__ attn){
  const int tid = threadIdx.x;
  const int wave = tid >> 6, lane = tid & 63;
  const int tok = blockIdx.x * 4 + wave;
  const int base = (tok >> 12) << 12;   // n*4096
  const f4* EK4 = (const f4*)EK;
  const f4* EV4 = (const f4*)EV;
  const f4* kvc4 = (const f4*)kvc;
  f4 qv  = *((const f4*)q + (size_t)tok * 64 + lane);
  f4 wk0 = kvc4[lane], wk1 = kvc4[64 + lane], bkv = kvc4[128 + lane];
  f4 wv0 = kvc4[192 + lane], wv1 = kvc4[256 + lane], bvv = kvc4[320 + lane];
  float sc[16];
  // pass 1: scores
  #pragma unroll
  for (int s = 0; s < 16; s++){
    float y = locb[tok * 32 + s * 2], x = locb[tok * 32 + s * 2 + 1];
    float o0 = offb[tok * 32 + s * 2], o1 = offb[tok * 32 + s * 2 + 1];
    float yf = floorf(y), xf = floorf(x);
    int y0 = (int)yf, x0 = (int)xf;
    int y1 = min(y0 + 1, 63), x1 = min(x0 + 1, 63);
    float wy = y - yf, wx = x - xf;
    f4 v00 = EK4[(size_t)(base + y0 * 64 + x0) * 64 + lane];
    f4 v01 = EK4[(size_t)(base + y0 * 64 + x1) * 64 + lane];
    f4 v10 = EK4[(size_t)(base + y1 * 64 + x0) * 64 + lane];
    f4 v11 = EK4[(size_t)(base + y1 * 64 + x1) * 64 + lane];
    f4 kv = ((1.f - wy) * (1.f - wx)) * v00 + ((1.f - wy) * wx) * v01
          + (wy * (1.f - wx)) * v10 + (wy * wx) * v11;
    kv += o0 * wk0 + o1 * wk1 + bkv;
    float p = qv.x * kv.x + qv.y * kv.y + qv.z * kv.z + qv.w * kv.w;
    p += __shfl_xor(p, 1); p += __shfl_xor(p, 2);
    p += __shfl_xor(p, 4); p += __shfl_xor(p, 8);
    sc[s] = p * 0.125f;   // /sqrt(64)
  }
  // softmax over s (per head; lanes in a head group hold identical sc[])
  float mx = sc[0];
  #pragma unroll
  for (int s = 1; s < 16; s++) mx = fmaxf(mx, sc[s]);
  float sum = 0.f;
  #pragma unroll
  for (int s = 0; s < 16; s++){ sc[s] = __expf(sc[s] - mx); sum += sc[s]; }
  float inv = 1.f / sum;
  #pragma unroll
  for (int s = 0; s < 16; s++) sc[s] *= inv;
  // pass 2: weighted V accumulate
  f4 acc = {0.f, 0.f, 0.f, 0.f};
  #pragma unroll
  for (int s = 0; s < 16; s++){
    float y = locb[tok * 32 + s * 2], x = locb[tok * 32 + s * 2 + 1];
    float o0 = offb[tok * 32 + s * 2], o1 = offb[tok * 32 + s * 2 + 1];
    float yf = floorf(y), xf = floorf(x);
    int y0 = (int)yf, x0 = (int)xf;
    int y1 = min(y0 + 1, 63), x1 = min(x0 + 1, 63);
    float wy = y - yf, wx = x - xf;
    f4 v00 = EV4[(size_t)(base + y0 * 64 + x0) * 64 + lane];
    f4 v01 = EV4[(size_t)(base + y0 * 64 + x1) * 64 + lane];
    f4 v10 = EV4[(size_t)(base + y1 * 64 + x0) * 64 + lane];
    f4 v11 = EV4[(size_t)(base + y1 * 64 + x1) * 64 + lane];
    f4 vv = ((1.f - wy) * (1.f - wx)) * v00 + ((1.f - wy) * wx) * v01
          + (wy * (1.f - wx)) * v10 + (wy * wx) * v11;
    vv += o0 * wv0 + o1 * wv1 + bvv;
    acc += sc[s] * vv;
  }
  *((f4*)attn + (size_t)tok * 64 + lane) = acc;
}

// ---------------------------------------------------------------------------
// LayerNorm(a + b) * scale + bias -> fp32. One wave per token. All fp32.
// ---------------------------------------------------------------------------
__global__ __launch_bounds__(256) void ln_k(const float* __restrict__ a,
                                            const float* __restrict__ b,
                                            const float* __restrict__ sc,
                                            const float* __restrict__ bi,
                                            float* __restrict__ out){
  const int tid = threadIdx.x;
  const int wave = tid >> 6, lane = tid & 63;
  const int tok = blockIdx.x * 4 + wave;
  f4 av = *((const f4*)a + (size_t)tok * 64 + lane);
  f4 bv = *((const f4*)b + (size_t)tok * 64 + lane);
  float x0 = av.x + bv.x, x1 = av.y + bv.y, x2 = av.z + bv.z, x3 = av.w + bv.w;
  float sm = x0 + x1 + x2 + x3;
  float sq = x0 * x0 + x1 * x1 + x2 * x2 + x3 * x3;
  #pragma unroll
  for (int m = 1; m < 64; m <<= 1){ sm += __shfl_xor(sm, m); sq += __shfl_xor(sq, m); }
  float mean = sm * (1.f / 256.f);
  float var = sq * (1.f / 256.f) - mean * mean;
  float rs = rsqrtf(var + 1e-6f);
  f4 sv = *((const f4*)sc + lane);
  f4 bb = *((const f4*)bi + lane);
  f4 ov;
  ov.x = (x0 - mean) * rs * sv.x + bb.x;
  ov.y = (x1 - mean) * rs * sv.y + bb.y;
  ov.z = (x2 - mean) * rs * sv.z + bb.z;
  ov.w = (x3 - mean) * rs * sv.w + bb.w;
  *((f4*)out + (size_t)tok * 64 + lane) = ov;
}

// ---------------------------------------------------------------------------
extern "C" void kernel_launch(void* const* d_in, const int* in_sizes, int n_in,
                              void* d_out, int out_size, void* d_ws, size_t ws_size,
                              hipStream_t stream){
  // setup_inputs() dict order (NOTE: ln2 before W1!) — all fp32
  const float* hs   = (const float*)d_in[0];
  const float* emb  = (const float*)d_in[1];
  const float* Woff = (const float*)d_in[2];
  const float* boff = (const float*)d_in[3];
  const float* Wkvp = (const float*)d_in[4];
  const float* bkvp = (const float*)d_in[5];
  const float* Wq   = (const float*)d_in[6];
  const float* bq   = (const float*)d_in[7];
  const float* Wk   = (const float*)d_in[8];
  const float* bk   = (const float*)d_in[9];
  const float* Wv   = (const float*)d_in[10];
  const float* bv   = (const float*)d_in[11];
  const float* Wo   = (const float*)d_in[12];
  const float* bo   = (const float*)d_in[13];
  const float* ln1s = (const float*)d_in[14];
  const float* ln1b = (const float*)d_in[15];
  const float* ln2s = (const float*)d_in[16];
  const float* ln2b = (const float*)d_in[17];
  const float* W1   = (const float*)d_in[18];
  const float* b1   = (const float*)d_in[19];
  const float* W2   = (const float*)d_in[20];
  const float* b2   = (const float*)d_in[21];

  char* w = (char*)d_ws;
  auto alloc = [&](size_t bytes){ char* p = w; w += (bytes + 255) & ~(size_t)255; return p; };
  u16* WqTh = (u16*)alloc(65536 * 2);  u16* WqTl = (u16*)alloc(65536 * 2);
  u16* WkTh = (u16*)alloc(65536 * 2);  u16* WkTl = (u16*)alloc(65536 * 2);
  u16* WvTh = (u16*)alloc(65536 * 2);  u16* WvTl = (u16*)alloc(65536 * 2);
  u16* WoTh = (u16*)alloc(65536 * 2);  u16* WoTl = (u16*)alloc(65536 * 2);
  u16* W1Th = (u16*)alloc(262144 * 2); u16* W1Tl = (u16*)alloc(262144 * 2);
  u16* W2Th = (u16*)alloc(262144 * 2); u16* W2Tl = (u16*)alloc(262144 * 2);
  float* kvc = (float*)alloc(1536 * 4);
  float* off = (float*)alloc(262144 * 4);
  float* loc = (float*)alloc(262144 * 4);
  // 32 MB contiguous block: qb, EK, EV, attnf — dead after out-proj; h1 overlays it
  float* qb    = (float*)alloc((size_t)NT * 256 * 4);
  float* EK    = (float*)alloc((size_t)NT * 256 * 4);
  float* EV    = (float*)alloc((size_t)NT * 256 * 4);
  float* attnf = (float*)alloc((size_t)NT * 256 * 4);
  float* aout  = (float*)alloc((size_t)NT * 256 * 4);
  float* xb    = (float*)alloc((size_t)NT * 256 * 4);
  float* h1    = qb;    // overlay: [NT,1024] fp32 = 32 MB over qb..attnf
  float* mout  = aout;  // overlay: aout dead after ln1
  if ((size_t)(w - (char*)d_ws) > ws_size) return;  // ws too small -> visible fail

  // weight prep (hi/lo split planes)
  transpose3_k<<<dim3(8, 8),  256, 0, stream>>>(Wq, WqTh, WqTl, 256, 256);
  transpose3_k<<<dim3(8, 8),  256, 0, stream>>>(Wk, WkTh, WkTl, 256, 256);
  transpose3_k<<<dim3(8, 8),  256, 0, stream>>>(Wv, WvTh, WvTl, 256, 256);
  transpose3_k<<<dim3(8, 8),  256, 0, stream>>>(Wo, WoTh, WoTl, 256, 256);
  transpose3_k<<<dim3(32, 8), 256, 0, stream>>>(W1, W1Th, W1Tl, 256, 1024);
  transpose3_k<<<dim3(8, 32), 256, 0, stream>>>(W2, W2Th, W2Tl, 1024, 256);
  prepkv_k<<<1, 256, 0, stream>>>(Wkvp, bkvp, Wk, bk, kvc);
  prepkv_k<<<1, 256, 0, stream>>>(Wkvp, bkvp, Wv, bv, kvc + 768);

  // offsets + sampling locations (fp32 throughout)
  offsets_k<<<1024, 256, 0, stream>>>(hs, Woff, boff, off, loc);

  // projections (bilinear commutes with linear proj: project THEN gather)
  gemm3_k<0><<<dim3(128, 4), 256, 0, stream>>>(hs,  WqTh, WqTl, bq,      qb, NT, 256, 256);
  gemm3_k<0><<<dim3(128, 4), 256, 0, stream>>>(emb, WkTh, WkTl, nullptr, EK, NT, 256, 256);
  gemm3_k<0><<<dim3(128, 4), 256, 0, stream>>>(emb, WvTh, WvTl, nullptr, EV, NT, 256, 256);

  // gather + attention
  attn_k<<<2048, 256, 0, stream>>>(qb, EK, EV, off, loc, kvc, attnf);

  // out-proj, LN1, MLP, LN2
  gemm3_k<0><<<dim3(128, 4),  256, 0, stream>>>(attnf, WoTh, WoTl, bo, aout, NT, 256, 256);
  ln_k<<<2048, 256, 0, stream>>>(hs, aout, ln1s, ln1b, xb);
  gemm3_k<2><<<dim3(128, 16), 256, 0, stream>>>(xb, W1Th, W1Tl, b1, h1, NT, 1024, 256);
  gemm3_k<0><<<dim3(128, 4),  256, 0, stream>>>(h1, W2Th, W2Tl, b2, mout, NT, 256, 1024);
  ln_k<<<2048, 256, 0, stream>>>(xb, mout, ln2s, ln2b, (float*)d_out);
}